// Round 11
// baseline (304.193 us; speedup 1.0000x reference)
//
#include <hip/hip_runtime.h>

// T=2048, B=16, D=1024
#define T_DIM 2048
#define B_DIM 16
#define D_DIM 1024
#define M_DIM (T_DIM * B_DIM)   // 32768
#define K_DIM D_DIM
#define N_DIM D_DIM
#define BD    (B_DIM * D_DIM)   // 16384 scan channels
#define NCH   32                // scan chunks
#define CHL   (T_DIM / NCH)     // 64 steps per chunk
#define NQ    (BD / 4)          // 4096 float4 channel-groups (legacy path)

typedef _Float16 f16;
typedef __attribute__((ext_vector_type(8)))  _Float16 f16x8;
typedef __attribute__((ext_vector_type(4)))  float    f32x4;

#define GLD16(g, l) __builtin_amdgcn_global_load_lds(                        \
    (const __attribute__((address_space(1))) unsigned*)(g),                  \
    (__attribute__((address_space(3))) unsigned*)(l), 16, 0, 0)

#define BARRIER do { asm volatile("" ::: "memory");                          \
                     __builtin_amdgcn_s_barrier();                           \
                     asm volatile("" ::: "memory"); } while (0)

// ---------- scan step helpers ----------
__device__ __forceinline__ void stepAB(float p, float& A, float& B) {
    const float ep  = __expf(-p);
    const float al  = __builtin_amdgcn_rcpf(1.f + ep);    // sigmoid(p)
    const float be  = ep * al;                             // 1-sigmoid(p)
    const float ep2 = ep * ep;
    const float th  = (1.f - ep2) * __builtin_amdgcn_rcpf(1.f + ep2); // tanh(p)
    A = A * al;
    B = fmaf(al, B, be * th);
}
__device__ __forceinline__ void stepH(float p, float& h) {
    const float ep  = __expf(-p);
    const float al  = __builtin_amdgcn_rcpf(1.f + ep);
    const float be  = ep * al;
    const float ep2 = ep * ep;
    const float th  = (1.f - ep2) * __builtin_amdgcn_rcpf(1.f + ep2);
    h = fmaf(al, h, be * th);
}
__device__ __forceinline__ float outOf(float h) {
    const float sh = __builtin_amdgcn_rcpf(1.f + __expf(-h));
    return h * h * sh;
}

// B tile format: per (bc, kt) tile of 128 cols x 64 k:
//   ushort idx = (c*128 + col)*8 + j, c = k>>3, j = k&7; tile = 16 KiB.
// A tiles are built in-kernel from f32 x with an XOR row-swizzle per plane:
//   slot(row,c) = ((row&15)^c)*16 + (row>>4)*256 bytes within plane c
//   -> staging ds_write conflict-free, fragment ds_read 2-way (free).

// ---------- pre-pass: W fp32 -> Wh f16 (tiled, 128-col slabs) ----------
__global__ __launch_bounds__(256) void convert_w(const float* __restrict__ W,
                                                 ushort* __restrict__ Wh) {
    __shared__ ushort th[8192];
    const int b   = (int)blockIdx.x;     // 128 = 8 bc x 16 kt
    const int bc  = b >> 4;
    const int kt  = b & 15;
    const int tid = (int)threadIdx.x;
#pragma unroll
    for (int i = 0; i < 8; ++i) {
        const int fi  = tid + i * 256;
        const int col = fi >> 4;
        const int kq  = fi & 15;
        const float4 v = *(const float4*)&W[(size_t)(bc * 128 + col) * K_DIM + kt * 64 + kq * 4];
        ushort4 u;
        u.x = __builtin_bit_cast(unsigned short, (f16)v.x);
        u.y = __builtin_bit_cast(unsigned short, (f16)v.y);
        u.z = __builtin_bit_cast(unsigned short, (f16)v.z);
        u.w = __builtin_bit_cast(unsigned short, (f16)v.w);
        const int idx = ((kq >> 1) * 128 + col) * 8 + (kq & 1) * 4;
        *(ushort4*)&th[idx] = u;
    }
    __syncthreads();
    const uint4* s = (const uint4*)th;
    uint4* d = (uint4*)(Wh + (size_t)b * 8192);
#pragma unroll
    for (int i = 0; i < 4; ++i) d[tid + i * 256] = s[tid + i * 256];
}

// ---------- Fused GEMM: proj = f16(x) * Wh^T + b  (16x16x32 MFMA) ----------
// K-tile order rotated per block (t0 = br & 15) to break HBM partition
// camping: lockstep K-phases put every A-load at the same addr mod 4KB.
// Same-br blocks share t0 (keep L2 x-line sharing); br-classes spread
// uniformly over all 16 column phases.
template <int OUT16>
__global__ __launch_bounds__(256, 2) void gemm_fused(const float* __restrict__ x,
                                                     const ushort* __restrict__ Wh,
                                                     const float* __restrict__ bias,
                                                     float* __restrict__ proj32,
                                                     ushort* __restrict__ proj16) {
    __shared__ ushort sA[2][8192];
    __shared__ ushort sB[2][8192];

    const int bid = (int)blockIdx.x;                 // 2048 blocks
    const int swz = (bid & 7) * 256 + (bid >> 3);    // XCD x owns br in [x*32, x*32+32)
    const int bc  = swz & 7;
    const int br  = swz >> 3;
    const int tid  = (int)threadIdx.x;
    const int lane = tid & 63;
    const int wid  = tid >> 6;
    const int wr = (wid >> 1) * 64;
    const int wc = (wid & 1) * 64;
    const int l16 = lane & 15;
    const int lc  = lane >> 4;
    const int t0  = br & 15;               // per-block K-phase rotation

    const float* xg = x + (size_t)(br * 128) * K_DIM;
    const char*  bG = (const char*)(Wh + (size_t)bc * 16 * 8192);

    // A staging map: thread owns (row0 + 16i, kq), i = 0..7 (coalesced 16-lane rows)
    const int row0 = tid >> 4;             // 0..15
    const int kq   = tid & 15;             // float4 column within the 64-k row
    const unsigned aoff0 = ((unsigned)row0 * 1024u + (unsigned)kq * 4u) * 4u;  // bytes
    const int cA = kq >> 1;                // k-plane 0..7
    const int lbyte0 = cA * 2048 + ((row0 ^ cA) * 16) + (kq & 1) * 8;  // swizzled slot

    f32x4 acc[4][4];
#pragma unroll
    for (int m = 0; m < 4; ++m)
#pragma unroll
        for (int n = 0; n < 4; ++n)
#pragma unroll
            for (int r = 0; r < 4; ++r) acc[m][n][r] = 0.f;

    float4 rx[8];

#define ISSUE_A(t) do {                                                       \
        const char* ab_ = (const char*)xg + aoff0 + (size_t)(t) * 256;        \
        _Pragma("unroll")                                                     \
        for (int i = 0; i < 8; ++i)                                           \
            rx[i] = *(const float4*)(ab_ + (size_t)i * 65536);                \
    } while (0)

#define CVT_A(buf) do {                                                       \
        char* lb_ = (char*)&sA[buf][0] + lbyte0;                              \
        _Pragma("unroll")                                                     \
        for (int i = 0; i < 8; ++i) {                                         \
            const unsigned short u0 = __builtin_bit_cast(unsigned short, (f16)rx[i].x); \
            const unsigned short u1 = __builtin_bit_cast(unsigned short, (f16)rx[i].y); \
            const unsigned short u2 = __builtin_bit_cast(unsigned short, (f16)rx[i].z); \
            const unsigned short u3 = __builtin_bit_cast(unsigned short, (f16)rx[i].w); \
            uint2 pk_;                                                        \
            pk_.x = (unsigned)u0 | ((unsigned)u1 << 16);                      \
            pk_.y = (unsigned)u2 | ((unsigned)u3 << 16);                      \
            *(uint2*)(lb_ + i * 256) = pk_;                                   \
        }                                                                     \
    } while (0)

#define ISSUE_B(t, buf) do {                                                  \
        const size_t tb_ = (size_t)(t) * 16384;                               \
        GLD16(bG + tb_ + tid * 16,         (char*)&sB[buf][0] + tid * 16);    \
        GLD16(bG + tb_ + tid * 16 + 4096,  (char*)&sB[buf][0] + tid * 16 + 4096);  \
        GLD16(bG + tb_ + tid * 16 + 8192,  (char*)&sB[buf][0] + tid * 16 + 8192);  \
        GLD16(bG + tb_ + tid * 16 + 12288, (char*)&sB[buf][0] + tid * 16 + 12288); \
    } while (0)

#define MFMA_TILE(buf) do {                                                   \
        _Pragma("unroll")                                                     \
        for (int kc = 0; kc < 2; ++kc) {                                      \
            const int c_  = kc * 4 + lc;                                      \
            const int ab_ = (c_ * 128 + wr + (l16 ^ c_)) * 8;                 \
            const int bb_ = (c_ * 128 + wc + l16) * 8;                        \
            f16x8 fa[4], fb[4];                                               \
            _Pragma("unroll")                                                 \
            for (int m = 0; m < 4; ++m)                                       \
                fa[m] = *(const f16x8*)&sA[buf][ab_ + m * 128];               \
            _Pragma("unroll")                                                 \
            for (int n = 0; n < 4; ++n)                                       \
                fb[n] = *(const f16x8*)&sB[buf][bb_ + n * 128];               \
            _Pragma("unroll")                                                 \
            for (int m = 0; m < 4; ++m)                                       \
                _Pragma("unroll")                                             \
                for (int n = 0; n < 4; ++n)                                   \
                    acc[m][n] = __builtin_amdgcn_mfma_f32_16x16x32_f16(       \
                        fa[m], fb[n], acc[m][n], 0, 0, 0);                    \
        }                                                                     \
    } while (0)

    // Prologue: stage tile t0 (full drain, one-time).
    ISSUE_A(t0);
    ISSUE_B(t0, 0);
    CVT_A(0);                                             // compiler waits rx
    asm volatile("s_waitcnt vmcnt(0)" ::: "memory");      // B(t0) landed
    asm volatile("s_waitcnt lgkmcnt(0)" ::: "memory");    // own ds_writes done
    BARRIER;

    for (int tt = 0; tt < 16; ++tt) {
        const int cur = tt & 1;
        const int nxt = cur ^ 1;
        const int tn  = (t0 + tt + 1) & 15;   // next tile in rotated order
        if (tt < 15) {
            ISSUE_A(tn);             // f32 x -> rx (latency under MFMA below)
            ISSUE_B(tn, nxt);        // DMA into the other buffer
        }
        MFMA_TILE(cur);
        if (tt < 15) {
            CVT_A(nxt);                                       // waits rx (compiler)
            asm volatile("s_waitcnt vmcnt(0)" ::: "memory");  // only B(tn) left
            asm volatile("s_waitcnt lgkmcnt(0)" ::: "memory");
        }
        BARRIER;
    }
#undef ISSUE_A
#undef CVT_A
#undef ISSUE_B
#undef MFMA_TILE

    // C/D layout (16x16): col = lane&15, row = (lane>>4)*4 + r   (verified r6/r7)
#pragma unroll
    for (int n = 0; n < 4; ++n) {
        const int colg = bc * 128 + wc + n * 16 + l16;
        const float bz = bias[colg];
#pragma unroll
        for (int m = 0; m < 4; ++m) {
            const int rowg = br * 128 + wr + m * 16 + lc * 4;
#pragma unroll
            for (int r = 0; r < 4; ++r) {
                const float v = acc[m][n][r] + bz;
                if constexpr (OUT16)
                    proj16[(size_t)(rowg + r) * N_DIM + colg] =
                        __builtin_bit_cast(unsigned short, (f16)v);
                else
                    proj32[(size_t)(rowg + r) * N_DIM + colg] = v;
            }
        }
    }
}

// ---------- Scan pass 1 (f16 proj, 8 channels/thread) ----------
__global__ __launch_bounds__(256) void scan_pass1h(const ushort* __restrict__ po,
                                                   float* __restrict__ Ac,
                                                   float* __restrict__ Bc) {
    const int blk = (int)blockIdx.x;         // 248 = 31 chunks x 8
    const int c   = blk >> 3;
    const int q   = (blk & 7) * 256 + (int)threadIdx.x;   // 0..2047
    const ushort* pp = po + (size_t)c * CHL * BD + (size_t)q * 8;

    float A[8], B[8];
#pragma unroll
    for (int e = 0; e < 8; ++e) { A[e] = 1.f; B[e] = 0.f; }

    f16x8 cur[4], nxt[4];
#pragma unroll
    for (int j = 0; j < 4; ++j) cur[j] = *(const f16x8*)&pp[(size_t)j * BD];
    for (int g = 0; g < CHL / 4; ++g) {
        if (g + 1 < CHL / 4) {
#pragma unroll
            for (int j = 0; j < 4; ++j)
                nxt[j] = *(const f16x8*)&pp[(size_t)((g + 1) * 4 + j) * BD];
        }
#pragma unroll
        for (int j = 0; j < 4; ++j)
#pragma unroll
            for (int e = 0; e < 8; ++e)
                stepAB((float)cur[j][e], A[e], B[e]);
#pragma unroll
        for (int j = 0; j < 4; ++j) cur[j] = nxt[j];
    }
    float* ap = Ac + (size_t)c * BD + (size_t)q * 8;
    float* bp = Bc + (size_t)c * BD + (size_t)q * 8;
    *(float4*)&ap[0] = make_float4(A[0], A[1], A[2], A[3]);
    *(float4*)&ap[4] = make_float4(A[4], A[5], A[6], A[7]);
    *(float4*)&bp[0] = make_float4(B[0], B[1], B[2], B[3]);
    *(float4*)&bp[4] = make_float4(B[4], B[5], B[6], B[7]);
}

// ---------- Scan pass 2 (f16 proj in ws -> f32 out + h) ----------
__global__ __launch_bounds__(256) void scan_pass2h(const ushort* __restrict__ po,
                                                   const float* __restrict__ Ac,
                                                   const float* __restrict__ Bc,
                                                   float* __restrict__ out,
                                                   float* __restrict__ h_out) {
    const int blk = (int)blockIdx.x;         // 256 = 32 chunks x 8
    const int c   = blk >> 3;
    const int q   = (blk & 7) * 256 + (int)threadIdx.x;

    float h[8];
#pragma unroll
    for (int e = 0; e < 8; ++e) h[e] = 0.f;
    for (int j = 0; j < c; ++j) {
        const float* ap = Ac + (size_t)j * BD + (size_t)q * 8;
        const float* bp = Bc + (size_t)j * BD + (size_t)q * 8;
        const float4 a0 = *(const float4*)&ap[0], a1 = *(const float4*)&ap[4];
        const float4 b0 = *(const float4*)&bp[0], b1 = *(const float4*)&bp[4];
        h[0] = fmaf(a0.x, h[0], b0.x); h[1] = fmaf(a0.y, h[1], b0.y);
        h[2] = fmaf(a0.z, h[2], b0.z); h[3] = fmaf(a0.w, h[3], b0.w);
        h[4] = fmaf(a1.x, h[4], b1.x); h[5] = fmaf(a1.y, h[5], b1.y);
        h[6] = fmaf(a1.z, h[6], b1.z); h[7] = fmaf(a1.w, h[7], b1.w);
    }
    if (c == 0) {
        *(float4*)&h_out[(size_t)q * 8]     = make_float4(0.f, 0.f, 0.f, 0.f);
        *(float4*)&h_out[(size_t)q * 8 + 4] = make_float4(0.f, 0.f, 0.f, 0.f);
    }

    const ushort* pp = po + (size_t)c * CHL * BD + (size_t)q * 8;
    float* op = out   + (size_t)c * CHL * BD + (size_t)q * 8;
    float* hp = h_out + (size_t)c * CHL * BD + (size_t)q * 8 + BD;   // h[t+1]

    f16x8 cur[4], nxt[4];
#pragma unroll
    for (int j = 0; j < 4; ++j) cur[j] = *(const f16x8*)&pp[(size_t)j * BD];
    for (int g = 0; g < CHL / 4; ++g) {
        if (g + 1 < CHL / 4) {
#pragma unroll
            for (int j = 0; j < 4; ++j)
                nxt[j] = *(const f16x8*)&pp[(size_t)((g + 1) * 4 + j) * BD];
        }
#pragma unroll
        for (int j = 0; j < 4; ++j) {
            const size_t so = (size_t)(g * 4 + j) * BD;
            float o[8];
#pragma unroll
            for (int e = 0; e < 8; ++e) {
                stepH((float)cur[j][e], h[e]);
                o[e] = outOf(h[e]);
            }
            *(float4*)&op[so]     = make_float4(o[0], o[1], o[2], o[3]);
            *(float4*)&op[so + 4] = make_float4(o[4], o[5], o[6], o[7]);
            *(float4*)&hp[so]     = make_float4(h[0], h[1], h[2], h[3]);
            *(float4*)&hp[so + 4] = make_float4(h[4], h[5], h[6], h[7]);
        }
#pragma unroll
        for (int j = 0; j < 4; ++j) cur[j] = nxt[j];
    }
}

// ---------- legacy f32-proj scan passes (fallback if ws is small) ----------
__global__ __launch_bounds__(256) void scan_pass1(const float* __restrict__ po,
                                                  float4* __restrict__ Ac,
                                                  float4* __restrict__ Bc) {
    const int blk = (int)blockIdx.x;         // 496 = 31 x 16
    const int c   = blk >> 4;
    const int q   = (blk & 15) * 256 + (int)threadIdx.x;
    const float* pp = po + (size_t)c * CHL * BD + (size_t)q * 4;

    float4 A = make_float4(1.f, 1.f, 1.f, 1.f);
    float4 B = make_float4(0.f, 0.f, 0.f, 0.f);
    float4 cur[4], nxt[4];
#pragma unroll
    for (int j = 0; j < 4; ++j) cur[j] = *(const float4*)&pp[(size_t)j * BD];
    for (int g = 0; g < CHL / 4; ++g) {
        if (g + 1 < CHL / 4) {
#pragma unroll
            for (int j = 0; j < 4; ++j)
                nxt[j] = *(const float4*)&pp[(size_t)((g + 1) * 4 + j) * BD];
        }
#pragma unroll
        for (int j = 0; j < 4; ++j) {
            stepAB(cur[j].x, A.x, B.x);
            stepAB(cur[j].y, A.y, B.y);
            stepAB(cur[j].z, A.z, B.z);
            stepAB(cur[j].w, A.w, B.w);
        }
#pragma unroll
        for (int j = 0; j < 4; ++j) cur[j] = nxt[j];
    }
    Ac[c * NQ + q] = A;
    Bc[c * NQ + q] = B;
}

__global__ __launch_bounds__(256) void scan_pass2(float* __restrict__ po,
                                                  const float4* __restrict__ Ac,
                                                  const float4* __restrict__ Bc,
                                                  float* __restrict__ h_out) {
    const int blk = (int)blockIdx.x;         // 512 = 32 x 16
    const int c   = blk >> 4;
    const int q   = (blk & 15) * 256 + (int)threadIdx.x;

    float4 h = make_float4(0.f, 0.f, 0.f, 0.f);
    for (int j = 0; j < c; ++j) {
        const float4 A = Ac[j * NQ + q];
        const float4 B = Bc[j * NQ + q];
        h.x = fmaf(A.x, h.x, B.x);
        h.y = fmaf(A.y, h.y, B.y);
        h.z = fmaf(A.z, h.z, B.z);
        h.w = fmaf(A.w, h.w, B.w);
    }
    if (c == 0) *(float4*)&h_out[(size_t)q * 4] = make_float4(0.f, 0.f, 0.f, 0.f);

    float* pp = po + (size_t)c * CHL * BD + (size_t)q * 4;
    float* hp = h_out + (size_t)c * CHL * BD + (size_t)q * 4 + BD;

    float4 cur[4], nxt[4];
#pragma unroll
    for (int j = 0; j < 4; ++j) cur[j] = *(const float4*)&pp[(size_t)j * BD];
    for (int g = 0; g < CHL / 4; ++g) {
        if (g + 1 < CHL / 4) {
#pragma unroll
            for (int j = 0; j < 4; ++j)
                nxt[j] = *(const float4*)&pp[(size_t)((g + 1) * 4 + j) * BD];
        }
#pragma unroll
        for (int j = 0; j < 4; ++j) {
            const size_t so = (size_t)(g * 4 + j) * BD;
            stepH(cur[j].x, h.x);
            stepH(cur[j].y, h.y);
            stepH(cur[j].z, h.z);
            stepH(cur[j].w, h.w);
            float4 o;
            o.x = outOf(h.x); o.y = outOf(h.y); o.z = outOf(h.z); o.w = outOf(h.w);
            *(float4*)&pp[so] = o;
            *(float4*)&hp[so] = h;
        }
#pragma unroll
        for (int j = 0; j < 4; ++j) cur[j] = nxt[j];
    }
}

// ---------- last-resort sequential scan ----------
__global__ __launch_bounds__(64) void scan_fused(float* __restrict__ po,
                                                 float* __restrict__ h_out) {
    const int idx = (int)blockIdx.x * 64 + (int)threadIdx.x;
    float h = 0.f;
    h_out[idx] = 0.f;
    size_t off = (size_t)idx;
#pragma unroll 4
    for (int t = 0; t < T_DIM; ++t) {
        float p = po[off];
        stepH(p, h);
        po[off] = outOf(h);
        h_out[off + BD] = h;
        off += BD;
    }
}

extern "C" void kernel_launch(void* const* d_in, const int* in_sizes, int n_in,
                              void* d_out, int out_size, void* d_ws, size_t ws_size,
                              hipStream_t stream) {
    const float* x = (const float*)d_in[0];
    const float* W = (const float*)d_in[1];
    const float* b = (const float*)d_in[2];
    float* out = (float*)d_out;                                // outputs (128 MB)
    float* h   = out + (size_t)T_DIM * B_DIM * D_DIM;          // h region (134.2 MB)

    // Wh scratch in the h region (dead before pass2 writes h):
    ushort* Wh = (ushort*)h;                                   // 2 MB

    convert_w<<<128, 256, 0, stream>>>(W, Wh);

    const size_t P16_BYTES = (size_t)M_DIM * N_DIM * 2;        // 64 MB
    const size_t AB_BYTES  = (size_t)NCH * BD * 4;             // 2 MB each

    if (ws_size >= P16_BYTES + 2 * AB_BYTES) {
        // f16 proj in workspace: half the proj write + both scan reads.
        ushort* P16 = (ushort*)d_ws;
        float*  Ac  = (float*)((char*)d_ws + P16_BYTES);
        float*  Bc  = Ac + (size_t)NCH * BD;
        gemm_fused<1><<<2048, 256, 0, stream>>>(x, Wh, b, nullptr, P16);
        scan_pass1h<<<(NCH - 1) * 8, 256, 0, stream>>>(P16, Ac, Bc);
        scan_pass2h<<<NCH * 8, 256, 0, stream>>>(P16, Ac, Bc, out, h);
    } else if (ws_size >= (size_t)4 * 1024 * 1024) {
        float4* Ac = (float4*)d_ws;
        float4* Bc = Ac + (size_t)NCH * NQ;
        gemm_fused<0><<<2048, 256, 0, stream>>>(x, Wh, b, out, nullptr);
        scan_pass1<<<(NCH - 1) * 16, 256, 0, stream>>>(out, Ac, Bc);
        scan_pass2<<<NCH * 16, 256, 0, stream>>>(out, Ac, Bc, h);
    } else {
        gemm_fused<0><<<2048, 256, 0, stream>>>(x, Wh, b, out, nullptr);
        scan_fused<<<BD / 64, 64, 0, stream>>>(out, h);
    }
}

// Round 12
// 221.080 us; speedup vs baseline: 1.3759x; 1.3759x over previous
//
#include <hip/hip_runtime.h>

// T=2048, B=16, D=1024
#define T_DIM 2048
#define B_DIM 16
#define D_DIM 1024
#define M_DIM (T_DIM * B_DIM)   // 32768
#define K_DIM D_DIM
#define N_DIM D_DIM
#define BD    (B_DIM * D_DIM)   // 16384 scan channels
#define NCH   32                // scan chunks
#define CHL   (T_DIM / NCH)     // 64 steps per chunk
#define NQ    (BD / 4)          // 4096 float4 channel-groups (legacy path)

typedef _Float16 f16;
typedef __attribute__((ext_vector_type(8)))  _Float16 f16x8;
typedef __attribute__((ext_vector_type(4)))  float    f32x4;

#define GLD16(g, l) __builtin_amdgcn_global_load_lds(                        \
    (const __attribute__((address_space(1))) unsigned*)(g),                  \
    (__attribute__((address_space(3))) unsigned*)(l), 16, 0, 0)

#define BARRIER do { asm volatile("" ::: "memory");                          \
                     __builtin_amdgcn_s_barrier();                           \
                     asm volatile("" ::: "memory"); } while (0)

// ---------- scan step helpers ----------
__device__ __forceinline__ void stepAB(float p, float& A, float& B) {
    const float ep  = __expf(-p);
    const float al  = __builtin_amdgcn_rcpf(1.f + ep);    // sigmoid(p)
    const float be  = ep * al;                             // 1-sigmoid(p)
    const float ep2 = ep * ep;
    const float th  = (1.f - ep2) * __builtin_amdgcn_rcpf(1.f + ep2); // tanh(p)
    A = A * al;
    B = fmaf(al, B, be * th);
}
__device__ __forceinline__ void stepH(float p, float& h) {
    const float ep  = __expf(-p);
    const float al  = __builtin_amdgcn_rcpf(1.f + ep);
    const float be  = ep * al;
    const float ep2 = ep * ep;
    const float th  = (1.f - ep2) * __builtin_amdgcn_rcpf(1.f + ep2);
    h = fmaf(al, h, be * th);
}
__device__ __forceinline__ float outOf(float h) {
    const float sh = __builtin_amdgcn_rcpf(1.f + __expf(-h));
    return h * h * sh;
}

// Tile format (A and B): per (slab, kt) tile of 128 rows x 32 k:
//   ushort idx = (c*128 + row)*8 + j, c = k>>3 (0..3), j = k&7; tile = 8 KiB.
//   (m97 geometry: 16 MFMA + 8 ds_read_b128 per K-iteration, 32 KiB LDS.)

// ---------- pre-pass 1: x fp32 -> Xf f16 (tiled, 128-row x 32-k) ----------
__global__ __launch_bounds__(256) void convert_x(const float* __restrict__ x,
                                                 ushort* __restrict__ Xf) {
    __shared__ ushort tile[4096];
    const int b   = (int)blockIdx.x;     // 8192 = 256 br x 32 kt
    const int br  = b >> 5;
    const int kt  = b & 31;
    const int tid = (int)threadIdx.x;
#pragma unroll
    for (int i = 0; i < 4; ++i) {
        const int fi  = tid + i * 256;   // 0..1023 float4s
        const int row = fi >> 3;         // 0..127
        const int kq  = fi & 7;          // float4 index within 32-k row
        const float4 v = *(const float4*)&x[(size_t)(br * 128 + row) * K_DIM + kt * 32 + kq * 4];
        ushort4 u;
        u.x = __builtin_bit_cast(unsigned short, (f16)v.x);
        u.y = __builtin_bit_cast(unsigned short, (f16)v.y);
        u.z = __builtin_bit_cast(unsigned short, (f16)v.z);
        u.w = __builtin_bit_cast(unsigned short, (f16)v.w);
        const int idx = ((kq >> 1) * 128 + row) * 8 + (kq & 1) * 4;
        *(ushort4*)&tile[idx] = u;
    }
    __syncthreads();
    const uint4* s = (const uint4*)tile;                 // 512 x 16B
    uint4* d = (uint4*)(Xf + (size_t)b * 4096);
    d[tid] = s[tid];
    d[tid + 256] = s[tid + 256];
}

// ---------- pre-pass 2: W fp32 -> Wh f16 (tiled, 128-col x 32-k) ----------
__global__ __launch_bounds__(256) void convert_w(const float* __restrict__ W,
                                                 ushort* __restrict__ Wh) {
    __shared__ ushort th[4096];
    const int b   = (int)blockIdx.x;     // 256 = 8 bc x 32 kt
    const int bc  = b >> 5;
    const int kt  = b & 31;
    const int tid = (int)threadIdx.x;
#pragma unroll
    for (int i = 0; i < 4; ++i) {
        const int fi  = tid + i * 256;
        const int col = fi >> 3;
        const int kq  = fi & 7;
        const float4 v = *(const float4*)&W[(size_t)(bc * 128 + col) * K_DIM + kt * 32 + kq * 4];
        ushort4 u;
        u.x = __builtin_bit_cast(unsigned short, (f16)v.x);
        u.y = __builtin_bit_cast(unsigned short, (f16)v.y);
        u.z = __builtin_bit_cast(unsigned short, (f16)v.z);
        u.w = __builtin_bit_cast(unsigned short, (f16)v.w);
        const int idx = ((kq >> 1) * 128 + col) * 8 + (kq & 1) * 4;
        *(ushort4*)&th[idx] = u;
    }
    __syncthreads();
    const uint4* s = (const uint4*)th;
    uint4* d = (uint4*)(Wh + (size_t)b * 4096);
    d[tid] = s[tid];
    d[tid + 256] = s[tid + 256];
}

// ---------- GEMM: proj = Xf * Wh^T + b  (16x16x32 MFMA, m97 geometry) ----------
// 128x128 block, BK=32, 4 waves (2x2), 4x4 frags/wave, 16 MFMA + 8 ds_read/iter.
// Double-buffered LDS 32 KiB -> up to 5 blocks/CU; counted vmcnt(4) prefetch.
template <int OUT16>
__global__ __launch_bounds__(256, 4) void gemm_proj(const ushort* __restrict__ Xf,
                                                    const ushort* __restrict__ Wh,
                                                    const float* __restrict__ bias,
                                                    float* __restrict__ proj32,
                                                    ushort* __restrict__ proj16) {
    __shared__ ushort sA[2][4096];   // 2 x 8 KiB
    __shared__ ushort sB[2][4096];   // 2 x 8 KiB

    const int bid = (int)blockIdx.x;                 // 2048 blocks
    const int swz = (bid & 7) * 256 + (bid >> 3);    // XCD x owns br in [x*32, x*32+32)
    const int bc  = swz & 7;
    const int br  = swz >> 3;
    const int tid  = (int)threadIdx.x;
    const int lane = tid & 63;
    const int wid  = tid >> 6;
    const int wr = (wid >> 1) * 64;
    const int wc = (wid & 1) * 64;
    const int l16 = lane & 15;
    const int lc  = lane >> 4;       // 0..3: k-plane

    const char* aG = (const char*)(Xf + (size_t)br * 32 * 4096);
    const char* bG = (const char*)(Wh + (size_t)bc * 32 * 4096);

    f32x4 acc[4][4];
#pragma unroll
    for (int m = 0; m < 4; ++m)
#pragma unroll
        for (int n = 0; n < 4; ++n)
#pragma unroll
            for (int r = 0; r < 4; ++r) acc[m][n][r] = 0.f;

#define STAGE(t, buf) do {                                                   \
        const size_t tb = (size_t)(t) * 8192;                                \
        GLD16(aG + tb + tid * 16,        (char*)&sA[buf][0] + tid * 16);     \
        GLD16(aG + tb + tid * 16 + 4096, (char*)&sA[buf][0] + tid * 16 + 4096); \
        GLD16(bG + tb + tid * 16,        (char*)&sB[buf][0] + tid * 16);     \
        GLD16(bG + tb + tid * 16 + 4096, (char*)&sB[buf][0] + tid * 16 + 4096); \
    } while (0)

    STAGE(0, 0);
    STAGE(1, 1);

    for (int t = 0; t < 32; ++t) {
        if (t < 31) asm volatile("s_waitcnt vmcnt(4)" ::: "memory");
        else        asm volatile("s_waitcnt vmcnt(0)" ::: "memory");
        BARRIER;
        const int cur = t & 1;
        {
            const int ab = (lc * 128 + wr + l16) * 8;
            const int bb = (lc * 128 + wc + l16) * 8;
            f16x8 fa[4], fb[4];
#pragma unroll
            for (int m = 0; m < 4; ++m)
                fa[m] = *(const f16x8*)&sA[cur][ab + m * 128];
#pragma unroll
            for (int n = 0; n < 4; ++n)
                fb[n] = *(const f16x8*)&sB[cur][bb + n * 128];
#pragma unroll
            for (int m = 0; m < 4; ++m)
#pragma unroll
                for (int n = 0; n < 4; ++n)
                    acc[m][n] = __builtin_amdgcn_mfma_f32_16x16x32_f16(fa[m], fb[n], acc[m][n], 0, 0, 0);
        }
        BARRIER;
        if (t < 30) STAGE(t + 2, cur);
    }
#undef STAGE

    // C/D layout (16x16): col = lane&15, row = (lane>>4)*4 + r   (verified r6/r7)
#pragma unroll
    for (int n = 0; n < 4; ++n) {
        const int colg = bc * 128 + wc + n * 16 + l16;
        const float bz = bias[colg];
#pragma unroll
        for (int m = 0; m < 4; ++m) {
            const int rowg = br * 128 + wr + m * 16 + lc * 4;
#pragma unroll
            for (int r = 0; r < 4; ++r) {
                const float v = acc[m][n][r] + bz;
                if constexpr (OUT16)
                    proj16[(size_t)(rowg + r) * N_DIM + colg] =
                        __builtin_bit_cast(unsigned short, (f16)v);
                else
                    proj32[(size_t)(rowg + r) * N_DIM + colg] = v;
            }
        }
    }
}

// ---------- Scan pass 1 (f16 proj, 8 channels/thread) ----------
__global__ __launch_bounds__(256) void scan_pass1h(const ushort* __restrict__ po,
                                                   float* __restrict__ Ac,
                                                   float* __restrict__ Bc) {
    const int blk = (int)blockIdx.x;         // 248 = 31 chunks x 8
    const int c   = blk >> 3;
    const int q   = (blk & 7) * 256 + (int)threadIdx.x;   // 0..2047
    const ushort* pp = po + (size_t)c * CHL * BD + (size_t)q * 8;

    float A[8], B[8];
#pragma unroll
    for (int e = 0; e < 8; ++e) { A[e] = 1.f; B[e] = 0.f; }

    f16x8 cur[4], nxt[4];
#pragma unroll
    for (int j = 0; j < 4; ++j) cur[j] = *(const f16x8*)&pp[(size_t)j * BD];
    for (int g = 0; g < CHL / 4; ++g) {
        if (g + 1 < CHL / 4) {
#pragma unroll
            for (int j = 0; j < 4; ++j)
                nxt[j] = *(const f16x8*)&pp[(size_t)((g + 1) * 4 + j) * BD];
        }
#pragma unroll
        for (int j = 0; j < 4; ++j)
#pragma unroll
            for (int e = 0; e < 8; ++e)
                stepAB((float)cur[j][e], A[e], B[e]);
#pragma unroll
        for (int j = 0; j < 4; ++j) cur[j] = nxt[j];
    }
    float* ap = Ac + (size_t)c * BD + (size_t)q * 8;
    float* bp = Bc + (size_t)c * BD + (size_t)q * 8;
    *(float4*)&ap[0] = make_float4(A[0], A[1], A[2], A[3]);
    *(float4*)&ap[4] = make_float4(A[4], A[5], A[6], A[7]);
    *(float4*)&bp[0] = make_float4(B[0], B[1], B[2], B[3]);
    *(float4*)&bp[4] = make_float4(B[4], B[5], B[6], B[7]);
}

// ---------- Scan pass 2 (f16 proj in ws -> f32 out + h) ----------
__global__ __launch_bounds__(256) void scan_pass2h(const ushort* __restrict__ po,
                                                   const float* __restrict__ Ac,
                                                   const float* __restrict__ Bc,
                                                   float* __restrict__ out,
                                                   float* __restrict__ h_out) {
    const int blk = (int)blockIdx.x;         // 256 = 32 chunks x 8
    const int c   = blk >> 3;
    const int q   = (blk & 7) * 256 + (int)threadIdx.x;

    float h[8];
#pragma unroll
    for (int e = 0; e < 8; ++e) h[e] = 0.f;
    for (int j = 0; j < c; ++j) {
        const float* ap = Ac + (size_t)j * BD + (size_t)q * 8;
        const float* bp = Bc + (size_t)j * BD + (size_t)q * 8;
        const float4 a0 = *(const float4*)&ap[0], a1 = *(const float4*)&ap[4];
        const float4 b0 = *(const float4*)&bp[0], b1 = *(const float4*)&bp[4];
        h[0] = fmaf(a0.x, h[0], b0.x); h[1] = fmaf(a0.y, h[1], b0.y);
        h[2] = fmaf(a0.z, h[2], b0.z); h[3] = fmaf(a0.w, h[3], b0.w);
        h[4] = fmaf(a1.x, h[4], b1.x); h[5] = fmaf(a1.y, h[5], b1.y);
        h[6] = fmaf(a1.z, h[6], b1.z); h[7] = fmaf(a1.w, h[7], b1.w);
    }
    if (c == 0) {
        *(float4*)&h_out[(size_t)q * 8]     = make_float4(0.f, 0.f, 0.f, 0.f);
        *(float4*)&h_out[(size_t)q * 8 + 4] = make_float4(0.f, 0.f, 0.f, 0.f);
    }

    const ushort* pp = po + (size_t)c * CHL * BD + (size_t)q * 8;
    float* op = out   + (size_t)c * CHL * BD + (size_t)q * 8;
    float* hp = h_out + (size_t)c * CHL * BD + (size_t)q * 8 + BD;   // h[t+1]

    f16x8 cur[4], nxt[4];
#pragma unroll
    for (int j = 0; j < 4; ++j) cur[j] = *(const f16x8*)&pp[(size_t)j * BD];
    for (int g = 0; g < CHL / 4; ++g) {
        if (g + 1 < CHL / 4) {
#pragma unroll
            for (int j = 0; j < 4; ++j)
                nxt[j] = *(const f16x8*)&pp[(size_t)((g + 1) * 4 + j) * BD];
        }
#pragma unroll
        for (int j = 0; j < 4; ++j) {
            const size_t so = (size_t)(g * 4 + j) * BD;
            float o[8];
#pragma unroll
            for (int e = 0; e < 8; ++e) {
                stepH((float)cur[j][e], h[e]);
                o[e] = outOf(h[e]);
            }
            *(float4*)&op[so]     = make_float4(o[0], o[1], o[2], o[3]);
            *(float4*)&op[so + 4] = make_float4(o[4], o[5], o[6], o[7]);
            *(float4*)&hp[so]     = make_float4(h[0], h[1], h[2], h[3]);
            *(float4*)&hp[so + 4] = make_float4(h[4], h[5], h[6], h[7]);
        }
#pragma unroll
        for (int j = 0; j < 4; ++j) cur[j] = nxt[j];
    }
}

// ---------- legacy f32-proj scan passes (fallback if ws is small) ----------
__global__ __launch_bounds__(256) void scan_pass1(const float* __restrict__ po,
                                                  float4* __restrict__ Ac,
                                                  float4* __restrict__ Bc) {
    const int blk = (int)blockIdx.x;         // 496 = 31 x 16
    const int c   = blk >> 4;
    const int q   = (blk & 15) * 256 + (int)threadIdx.x;
    const float* pp = po + (size_t)c * CHL * BD + (size_t)q * 4;

    float4 A = make_float4(1.f, 1.f, 1.f, 1.f);
    float4 B = make_float4(0.f, 0.f, 0.f, 0.f);
    float4 cur[4], nxt[4];
#pragma unroll
    for (int j = 0; j < 4; ++j) cur[j] = *(const float4*)&pp[(size_t)j * BD];
    for (int g = 0; g < CHL / 4; ++g) {
        if (g + 1 < CHL / 4) {
#pragma unroll
            for (int j = 0; j < 4; ++j)
                nxt[j] = *(const float4*)&pp[(size_t)((g + 1) * 4 + j) * BD];
        }
#pragma unroll
        for (int j = 0; j < 4; ++j) {
            stepAB(cur[j].x, A.x, B.x);
            stepAB(cur[j].y, A.y, B.y);
            stepAB(cur[j].z, A.z, B.z);
            stepAB(cur[j].w, A.w, B.w);
        }
#pragma unroll
        for (int j = 0; j < 4; ++j) cur[j] = nxt[j];
    }
    Ac[c * NQ + q] = A;
    Bc[c * NQ + q] = B;
}

__global__ __launch_bounds__(256) void scan_pass2(float* __restrict__ po,
                                                  const float4* __restrict__ Ac,
                                                  const float4* __restrict__ Bc,
                                                  float* __restrict__ h_out) {
    const int blk = (int)blockIdx.x;         // 512 = 32 x 16
    const int c   = blk >> 4;
    const int q   = (blk & 15) * 256 + (int)threadIdx.x;

    float4 h = make_float4(0.f, 0.f, 0.f, 0.f);
    for (int j = 0; j < c; ++j) {
        const float4 A = Ac[j * NQ + q];
        const float4 B = Bc[j * NQ + q];
        h.x = fmaf(A.x, h.x, B.x);
        h.y = fmaf(A.y, h.y, B.y);
        h.z = fmaf(A.z, h.z, B.z);
        h.w = fmaf(A.w, h.w, B.w);
    }
    if (c == 0) *(float4*)&h_out[(size_t)q * 4] = make_float4(0.f, 0.f, 0.f, 0.f);

    float* pp = po + (size_t)c * CHL * BD + (size_t)q * 4;
    float* hp = h_out + (size_t)c * CHL * BD + (size_t)q * 4 + BD;

    float4 cur[4], nxt[4];
#pragma unroll
    for (int j = 0; j < 4; ++j) cur[j] = *(const float4*)&pp[(size_t)j * BD];
    for (int g = 0; g < CHL / 4; ++g) {
        if (g + 1 < CHL / 4) {
#pragma unroll
            for (int j = 0; j < 4; ++j)
                nxt[j] = *(const float4*)&pp[(size_t)((g + 1) * 4 + j) * BD];
        }
#pragma unroll
        for (int j = 0; j < 4; ++j) {
            const size_t so = (size_t)(g * 4 + j) * BD;
            stepH(cur[j].x, h.x);
            stepH(cur[j].y, h.y);
            stepH(cur[j].z, h.z);
            stepH(cur[j].w, h.w);
            float4 o;
            o.x = outOf(h.x); o.y = outOf(h.y); o.z = outOf(h.z); o.w = outOf(h.w);
            *(float4*)&pp[so] = o;
            *(float4*)&hp[so] = h;
        }
#pragma unroll
        for (int j = 0; j < 4; ++j) cur[j] = nxt[j];
    }
}

// ---------- last-resort sequential scan ----------
__global__ __launch_bounds__(64) void scan_fused(float* __restrict__ po,
                                                 float* __restrict__ h_out) {
    const int idx = (int)blockIdx.x * 64 + (int)threadIdx.x;
    float h = 0.f;
    h_out[idx] = 0.f;
    size_t off = (size_t)idx;
#pragma unroll 4
    for (int t = 0; t < T_DIM; ++t) {
        float p = po[off];
        stepH(p, h);
        po[off] = outOf(h);
        h_out[off + BD] = h;
        off += BD;
    }
}

extern "C" void kernel_launch(void* const* d_in, const int* in_sizes, int n_in,
                              void* d_out, int out_size, void* d_ws, size_t ws_size,
                              hipStream_t stream) {
    const float* x = (const float*)d_in[0];
    const float* W = (const float*)d_in[1];
    const float* b = (const float*)d_in[2];
    float* out = (float*)d_out;                                // outputs (128 MB)
    float* h   = out + (size_t)T_DIM * B_DIM * D_DIM;          // h region (134.2 MB)

    // Xf/Wh scratch in the h region (dead before pass2 writes h):
    ushort* Xf = (ushort*)h;                                   // 64 MB
    ushort* Wh = Xf + (size_t)M_DIM * K_DIM;                   // 2 MB

    convert_x<<<8192, 256, 0, stream>>>(x, Xf);
    convert_w<<<256, 256, 0, stream>>>(W, Wh);

    const size_t P16_BYTES = (size_t)M_DIM * N_DIM * 2;        // 64 MB
    const size_t AB_BYTES  = (size_t)NCH * BD * 4;             // 2 MB each

    if (ws_size >= P16_BYTES + 2 * AB_BYTES) {
        // f16 proj in workspace: half the proj write + both scan reads.
        ushort* P16 = (ushort*)d_ws;
        float*  Ac  = (float*)((char*)d_ws + P16_BYTES);
        float*  Bc  = Ac + (size_t)NCH * BD;
        gemm_proj<1><<<2048, 256, 0, stream>>>(Xf, Wh, b, nullptr, P16);
        scan_pass1h<<<(NCH - 1) * 8, 256, 0, stream>>>(P16, Ac, Bc);
        scan_pass2h<<<NCH * 8, 256, 0, stream>>>(P16, Ac, Bc, out, h);
    } else if (ws_size >= (size_t)4 * 1024 * 1024) {
        float4* Ac = (float4*)d_ws;
        float4* Bc = Ac + (size_t)NCH * NQ;
        gemm_proj<0><<<2048, 256, 0, stream>>>(Xf, Wh, b, out, nullptr);
        scan_pass1<<<(NCH - 1) * 16, 256, 0, stream>>>(out, Ac, Bc);
        scan_pass2<<<NCH * 16, 256, 0, stream>>>(out, Ac, Bc, h);
    } else {
        gemm_proj<0><<<2048, 256, 0, stream>>>(Xf, Wh, b, out, nullptr);
        scan_fused<<<BD / 64, 64, 0, stream>>>(out, h);
    }
}

// Round 14
// 218.101 us; speedup vs baseline: 1.3947x; 1.0137x over previous
//
#include <hip/hip_runtime.h>

// T=2048, B=16, D=1024
#define T_DIM 2048
#define B_DIM 16
#define D_DIM 1024
#define M_DIM (T_DIM * B_DIM)   // 32768
#define K_DIM D_DIM
#define N_DIM D_DIM
#define BD    (B_DIM * D_DIM)   // 16384 scan channels
#define NCH   32                // scan chunks
#define CHL   (T_DIM / NCH)     // 64 steps per chunk
#define NQ    (BD / 4)          // 4096 float4 channel-groups (legacy path)

typedef _Float16 f16;
typedef __attribute__((ext_vector_type(8)))  _Float16 f16x8;
typedef __attribute__((ext_vector_type(4)))  float    f32x4;

#define GLD16(g, l) __builtin_amdgcn_global_load_lds(                        \
    (const __attribute__((address_space(1))) unsigned*)(g),                  \
    (__attribute__((address_space(3))) unsigned*)(l), 16, 0, 0)

#define BARRIER do { asm volatile("" ::: "memory");                          \
                     __builtin_amdgcn_s_barrier();                           \
                     asm volatile("" ::: "memory"); } while (0)

// ---------- scan step helpers ----------
__device__ __forceinline__ void stepAB(float p, float& A, float& B) {
    const float ep  = __expf(-p);
    const float al  = __builtin_amdgcn_rcpf(1.f + ep);    // sigmoid(p)
    const float be  = ep * al;                             // 1-sigmoid(p)
    const float ep2 = ep * ep;
    const float th  = (1.f - ep2) * __builtin_amdgcn_rcpf(1.f + ep2); // tanh(p)
    A = A * al;
    B = fmaf(al, B, be * th);
}
__device__ __forceinline__ void stepH(float p, float& h) {
    const float ep  = __expf(-p);
    const float al  = __builtin_amdgcn_rcpf(1.f + ep);
    const float be  = ep * al;
    const float ep2 = ep * ep;
    const float th  = (1.f - ep2) * __builtin_amdgcn_rcpf(1.f + ep2);
    h = fmaf(al, h, be * th);
}
__device__ __forceinline__ float outOf(float h) {
    const float sh = __builtin_amdgcn_rcpf(1.f + __expf(-h));
    return h * h * sh;
}

// Tile format (A and B): per (256-row slab, kt) tile of 256 rows x 64 k:
//   ushort idx = (c*256 + row)*8 + j, c = k>>3 (0..7), j = k&7; tile = 32 KiB.
// Fragment ds_read = 16 consecutive rows x 16B = contiguous: conflict-free.

// ---------- pre-pass: fp32 [rows][1024] -> f16 tiled (256-row slabs) ----------
__global__ __launch_bounds__(256) void convert_tiles(const float* __restrict__ src,
                                                     ushort* __restrict__ dst) {
    __shared__ ushort tile[16384];
    const int b   = (int)blockIdx.x;
    const int sr  = b >> 4;              // 256-row slab
    const int kt  = b & 15;
    const int tid = (int)threadIdx.x;
#pragma unroll
    for (int i = 0; i < 16; ++i) {
        const int fi  = tid + i * 256;   // 0..4095 float4s
        const int row = fi >> 4;         // 0..255
        const int kq  = fi & 15;         // float4 col within 64-k row
        const float4 v = *(const float4*)&src[(size_t)(sr * 256 + row) * K_DIM + kt * 64 + kq * 4];
        ushort4 u;
        u.x = __builtin_bit_cast(unsigned short, (f16)v.x);
        u.y = __builtin_bit_cast(unsigned short, (f16)v.y);
        u.z = __builtin_bit_cast(unsigned short, (f16)v.z);
        u.w = __builtin_bit_cast(unsigned short, (f16)v.w);
        const int idx = ((kq >> 1) * 256 + row) * 8 + (kq & 1) * 4;
        *(ushort4*)&tile[idx] = u;
    }
    __syncthreads();
    const uint4* s = (const uint4*)tile;                 // 2048 x 16B
    uint4* d = (uint4*)(dst + (size_t)b * 16384);
#pragma unroll
    for (int i = 0; i < 8; ++i) d[tid + i * 256] = s[tid + i * 256];
}

// ---------- GEMM: proj = Xf * Wh^T + b  (256x256 8-phase, 16x16x32 MFMA) ----------
// Counted-vmcnt ledger requires the VMEM queue to contain ONLY the staging
// GLD16s: all other loads (bias) are issued and drained (vmcnt(0)) BEFORE the
// prologue, so compiler hoisting cannot shift the ledger (r13 race root cause).
template <int OUT16>
__global__ __launch_bounds__(512, 1) void gemm_proj(const ushort* __restrict__ Xf,
                                                    const ushort* __restrict__ Wh,
                                                    const float* __restrict__ bias,
                                                    float* __restrict__ proj32,
                                                    ushort* __restrict__ proj16) {
    __shared__ ushort sA[2][16384];   // 2 x 32 KiB
    __shared__ ushort sB[2][16384];   // 2 x 32 KiB

    const int bid = (int)blockIdx.x;                 // 512 blocks
    const int swz = (bid & 7) * 64 + (bid >> 3);     // XCD x owns br in [x*16, x*16+16)
    const int bc  = swz & 3;                         // 0..3 (256-col tiles)
    const int br  = swz >> 2;                        // 0..127
    const int tid  = (int)threadIdx.x;
    const int lane = tid & 63;
    const int wid  = tid >> 6;
    const int wr = (wid >> 2) * 128;                 // 0 / 128
    const int wc = (wid & 3) * 64;                   // 0,64,128,192
    const int l16 = lane & 15;
    const int lc  = (lane >> 4) & 3;

    const char* aG = (const char*)(Xf + (size_t)br * 16 * 16384);
    const char* bG = (const char*)(Wh + (size_t)bc * 16 * 16384);

    // Pre-load bias into registers and DRAIN before any GLD16: keeps the
    // VMEM queue ledger exact (only staging loads counted by fences).
    float bz[4];
#pragma unroll
    for (int n = 0; n < 4; ++n)
        bz[n] = bias[bc * 256 + wc + n * 16 + l16];
    asm volatile("s_waitcnt vmcnt(0)" ::: "memory");

    f32x4 acc[8][4];
#pragma unroll
    for (int m = 0; m < 8; ++m)
#pragma unroll
        for (int n = 0; n < 4; ++n)
#pragma unroll
            for (int r = 0; r < 4; ++r) acc[m][n][r] = 0.f;

    // Stage calls: 512 thr x 16B = 8 KiB/call; A-tile = 32 KiB = 4 calls.
    // kc0 = calls 0,1 (planes 0-3), kc1 = calls 2,3. Issue order per tile:
    // A-kc0, B-kc0, A-kc1, B-kc1 -> oldest-4 at any fence = one kc half.
#define STG_A0(ST, SB_) do { const size_t tb_ = (size_t)(ST) * 32768;        \
        GLD16(aG + tb_ + tid * 16,        (char*)&sA[SB_][0] + tid * 16);    \
        GLD16(aG + tb_ + tid * 16 + 8192, (char*)&sA[SB_][0] + tid * 16 + 8192); } while (0)
#define STG_B0(ST, SB_) do { const size_t tb_ = (size_t)(ST) * 32768;        \
        GLD16(bG + tb_ + tid * 16,        (char*)&sB[SB_][0] + tid * 16);    \
        GLD16(bG + tb_ + tid * 16 + 8192, (char*)&sB[SB_][0] + tid * 16 + 8192); } while (0)
#define STG_A1(ST, SB_) do { const size_t tb_ = (size_t)(ST) * 32768;        \
        GLD16(aG + tb_ + tid * 16 + 16384, (char*)&sA[SB_][0] + tid * 16 + 16384); \
        GLD16(aG + tb_ + tid * 16 + 24576, (char*)&sA[SB_][0] + tid * 16 + 24576); } while (0)
#define STG_B1(ST, SB_) do { const size_t tb_ = (size_t)(ST) * 32768;        \
        GLD16(bG + tb_ + tid * 16 + 16384, (char*)&sB[SB_][0] + tid * 16 + 16384); \
        GLD16(bG + tb_ + tid * 16 + 24576, (char*)&sB[SB_][0] + tid * 16 + 24576); } while (0)

#define FENCE4 asm volatile("s_waitcnt vmcnt(4)" ::: "memory")
#define FENCE8 asm volatile("s_waitcnt vmcnt(8)" ::: "memory")
#define FENCE0 asm volatile("s_waitcnt vmcnt(0)" ::: "memory")

#define PHASE(BUF, KC, MG, STAGE_STMT, FENCE_STMT) do {                      \
        f16x8 fa[4], fb[4];                                                  \
        _Pragma("unroll")                                                    \
        for (int mm = 0; mm < 4; ++mm)                                       \
            fa[mm] = *(const f16x8*)&sA[BUF][(((KC)*4 + lc) * 256 + wr + ((MG)*4 + mm) * 16 + l16) * 8]; \
        _Pragma("unroll")                                                    \
        for (int nn = 0; nn < 4; ++nn)                                       \
            fb[nn] = *(const f16x8*)&sB[BUF][(((KC)*4 + lc) * 256 + wc + nn * 16 + l16) * 8]; \
        STAGE_STMT;                                                          \
        FENCE_STMT;                                                          \
        BARRIER;                                                             \
        __builtin_amdgcn_s_setprio(1);                                       \
        _Pragma("unroll")                                                    \
        for (int mm = 0; mm < 4; ++mm)                                       \
            _Pragma("unroll")                                                \
            for (int nn = 0; nn < 4; ++nn)                                   \
                acc[(MG)*4 + mm][nn] = __builtin_amdgcn_mfma_f32_16x16x32_f16( \
                    fa[mm], fb[nn], acc[(MG)*4 + mm][nn], 0, 0, 0);          \
        __builtin_amdgcn_s_setprio(0);                                       \
        BARRIER;                                                             \
    } while (0)

    // Prologue: tiles 0 -> buf0, 1 -> buf1 (A-kc0, B-kc0, A-kc1, B-kc1 each).
    STG_A0(0, 0); STG_B0(0, 0); STG_A1(0, 0); STG_B1(0, 0);
    STG_A0(1, 1); STG_B0(1, 1); STG_A1(1, 1); STG_B1(1, 1);
    FENCE4;                         // 12 landed: tile0 full + tile1 kc0; 4 left = tile1 kc1
    BARRIER;

    // K-tile 0 (buf0, no staging; already fully landed)
    PHASE(0, 0, 0, , );
    PHASE(0, 0, 1, , );
    PHASE(0, 1, 0, , );
    PHASE(0, 1, 1, , );

    // K-tiles 1..14: steady state. Odd tile reads buf1, stages t+1 -> buf0.
    for (int u = 0; u < 7; ++u) {
        const int t1 = 2 * u + 2;
        const int t2 = 2 * u + 3;
        PHASE(1, 0, 0, STG_A0(t1, 0), );
        PHASE(1, 0, 1, STG_B0(t1, 0), FENCE4);   // lands this tile's kc1 before phase3
        PHASE(1, 1, 0, STG_A1(t1, 0), );
        PHASE(1, 1, 1, STG_B1(t1, 0), FENCE4);   // lands next tile's kc0
        PHASE(0, 0, 0, STG_A0(t2, 1), );
        PHASE(0, 0, 1, STG_B0(t2, 1), FENCE4);
        PHASE(0, 1, 0, STG_A1(t2, 1), );
        PHASE(0, 1, 1, STG_B1(t2, 1), FENCE4);
    }

    // K-tile 15 (buf1, no staging; FENCE0 lands kc1 before phase3)
    PHASE(1, 0, 0, , );
    PHASE(1, 0, 1, , FENCE0);
    PHASE(1, 1, 0, , );
    PHASE(1, 1, 1, , );

#undef PHASE
#undef STG_A0
#undef STG_B0
#undef STG_A1
#undef STG_B1

    // C/D layout (16x16): col = lane&15, row = (lane>>4)*4 + r   (verified r6/r7)
#pragma unroll
    for (int n = 0; n < 4; ++n) {
        const int colg = bc * 256 + wc + n * 16 + l16;
#pragma unroll
        for (int m = 0; m < 8; ++m) {
            const int rowg = br * 256 + wr + m * 16 + lc * 4;
#pragma unroll
            for (int r = 0; r < 4; ++r) {
                const float v = acc[m][n][r] + bz[n];
                if constexpr (OUT16)
                    proj16[(size_t)(rowg + r) * N_DIM + colg] =
                        __builtin_bit_cast(unsigned short, (f16)v);
                else
                    proj32[(size_t)(rowg + r) * N_DIM + colg] = v;
            }
        }
    }
}

// ---------- Scan pass 1 (f16 proj, 8 channels/thread) ----------
__global__ __launch_bounds__(256) void scan_pass1h(const ushort* __restrict__ po,
                                                   float* __restrict__ Ac,
                                                   float* __restrict__ Bc) {
    const int blk = (int)blockIdx.x;         // 248 = 31 chunks x 8
    const int c   = blk >> 3;
    const int q   = (blk & 7) * 256 + (int)threadIdx.x;   // 0..2047
    const ushort* pp = po + (size_t)c * CHL * BD + (size_t)q * 8;

    float A[8], B[8];
#pragma unroll
    for (int e = 0; e < 8; ++e) { A[e] = 1.f; B[e] = 0.f; }

    f16x8 cur[4], nxt[4];
#pragma unroll
    for (int j = 0; j < 4; ++j) cur[j] = *(const f16x8*)&pp[(size_t)j * BD];
    for (int g = 0; g < CHL / 4; ++g) {
        if (g + 1 < CHL / 4) {
#pragma unroll
            for (int j = 0; j < 4; ++j)
                nxt[j] = *(const f16x8*)&pp[(size_t)((g + 1) * 4 + j) * BD];
        }
#pragma unroll
        for (int j = 0; j < 4; ++j)
#pragma unroll
            for (int e = 0; e < 8; ++e)
                stepAB((float)cur[j][e], A[e], B[e]);
#pragma unroll
        for (int j = 0; j < 4; ++j) cur[j] = nxt[j];
    }
    float* ap = Ac + (size_t)c * BD + (size_t)q * 8;
    float* bp = Bc + (size_t)c * BD + (size_t)q * 8;
    *(float4*)&ap[0] = make_float4(A[0], A[1], A[2], A[3]);
    *(float4*)&ap[4] = make_float4(A[4], A[5], A[6], A[7]);
    *(float4*)&bp[0] = make_float4(B[0], B[1], B[2], B[3]);
    *(float4*)&bp[4] = make_float4(B[4], B[5], B[6], B[7]);
}

// ---------- Scan pass 2 (f16 proj in ws -> f32 out + h) ----------
__global__ __launch_bounds__(256) void scan_pass2h(const ushort* __restrict__ po,
                                                   const float* __restrict__ Ac,
                                                   const float* __restrict__ Bc,
                                                   float* __restrict__ out,
                                                   float* __restrict__ h_out) {
    const int blk = (int)blockIdx.x;         // 256 = 32 chunks x 8
    const int c   = blk >> 3;
    const int q   = (blk & 7) * 256 + (int)threadIdx.x;

    float h[8];
#pragma unroll
    for (int e = 0; e < 8; ++e) h[e] = 0.f;
    for (int j = 0; j < c; ++j) {
        const float* ap = Ac + (size_t)j * BD + (size_t)q * 8;
        const float* bp = Bc + (size_t)j * BD + (size_t)q * 8;
        const float4 a0 = *(const float4*)&ap[0], a1 = *(const float4*)&ap[4];
        const float4 b0 = *(const float4*)&bp[0], b1 = *(const float4*)&bp[4];
        h[0] = fmaf(a0.x, h[0], b0.x); h[1] = fmaf(a0.y, h[1], b0.y);
        h[2] = fmaf(a0.z, h[2], b0.z); h[3] = fmaf(a0.w, h[3], b0.w);
        h[4] = fmaf(a1.x, h[4], b1.x); h[5] = fmaf(a1.y, h[5], b1.y);
        h[6] = fmaf(a1.z, h[6], b1.z); h[7] = fmaf(a1.w, h[7], b1.w);
    }
    if (c == 0) {
        *(float4*)&h_out[(size_t)q * 8]     = make_float4(0.f, 0.f, 0.f, 0.f);
        *(float4*)&h_out[(size_t)q * 8 + 4] = make_float4(0.f, 0.f, 0.f, 0.f);
    }

    const ushort* pp = po + (size_t)c * CHL * BD + (size_t)q * 8;
    float* op = out   + (size_t)c * CHL * BD + (size_t)q * 8;
    float* hp = h_out + (size_t)c * CHL * BD + (size_t)q * 8 + BD;   // h[t+1]

    f16x8 cur[4], nxt[4];
#pragma unroll
    for (int j = 0; j < 4; ++j) cur[j] = *(const f16x8*)&pp[(size_t)j * BD];
    for (int g = 0; g < CHL / 4; ++g) {
        if (g + 1 < CHL / 4) {
#pragma unroll
            for (int j = 0; j < 4; ++j)
                nxt[j] = *(const f16x8*)&pp[(size_t)((g + 1) * 4 + j) * BD];
        }
#pragma unroll
        for (int j = 0; j < 4; ++j) {
            const size_t so = (size_t)(g * 4 + j) * BD;
            float o[8];
#pragma unroll
            for (int e = 0; e < 8; ++e) {
                stepH((float)cur[j][e], h[e]);
                o[e] = outOf(h[e]);
            }
            *(float4*)&op[so]     = make_float4(o[0], o[1], o[2], o[3]);
            *(float4*)&op[so + 4] = make_float4(o[4], o[5], o[6], o[7]);
            *(float4*)&hp[so]     = make_float4(h[0], h[1], h[2], h[3]);
            *(float4*)&hp[so + 4] = make_float4(h[4], h[5], h[6], h[7]);
        }
#pragma unroll
        for (int j = 0; j < 4; ++j) cur[j] = nxt[j];
    }
}

// ---------- legacy f32-proj scan passes (fallback if ws is small) ----------
__global__ __launch_bounds__(256) void scan_pass1(const float* __restrict__ po,
                                                  float4* __restrict__ Ac,
                                                  float4* __restrict__ Bc) {
    const int blk = (int)blockIdx.x;         // 496 = 31 x 16
    const int c   = blk >> 4;
    const int q   = (blk & 15) * 256 + (int)threadIdx.x;
    const float* pp = po + (size_t)c * CHL * BD + (size_t)q * 4;

    float4 A = make_float4(1.f, 1.f, 1.f, 1.f);
    float4 B = make_float4(0.f, 0.f, 0.f, 0.f);
    float4 cur[4], nxt[4];
#pragma unroll
    for (int j = 0; j < 4; ++j) cur[j] = *(const float4*)&pp[(size_t)j * BD];
    for (int g = 0; g < CHL / 4; ++g) {
        if (g + 1 < CHL / 4) {
#pragma unroll
            for (int j = 0; j < 4; ++j)
                nxt[j] = *(const float4*)&pp[(size_t)((g + 1) * 4 + j) * BD];
        }
#pragma unroll
        for (int j = 0; j < 4; ++j) {
            stepAB(cur[j].x, A.x, B.x);
            stepAB(cur[j].y, A.y, B.y);
            stepAB(cur[j].z, A.z, B.z);
            stepAB(cur[j].w, A.w, B.w);
        }
#pragma unroll
        for (int j = 0; j < 4; ++j) cur[j] = nxt[j];
    }
    Ac[c * NQ + q] = A;
    Bc[c * NQ + q] = B;
}

__global__ __launch_bounds__(256) void scan_pass2(float* __restrict__ po,
                                                  const float4* __restrict__ Ac,
                                                  const float4* __restrict__ Bc,
                                                  float* __restrict__ h_out) {
    const int blk = (int)blockIdx.x;         // 512 = 32 x 16
    const int c   = blk >> 4;
    const int q   = (blk & 15) * 256 + (int)threadIdx.x;

    float4 h = make_float4(0.f, 0.f, 0.f, 0.f);
    for (int j = 0; j < c; ++j) {
        const float4 A = Ac[j * NQ + q];
        const float4 B = Bc[j * NQ + q];
        h.x = fmaf(A.x, h.x, B.x);
        h.y = fmaf(A.y, h.y, B.y);
        h.z = fmaf(A.z, h.z, B.z);
        h.w = fmaf(A.w, h.w, B.w);
    }
    if (c == 0) *(float4*)&h_out[(size_t)q * 4] = make_float4(0.f, 0.f, 0.f, 0.f);

    float* pp = po + (size_t)c * CHL * BD + (size_t)q * 4;
    float* hp = h_out + (size_t)c * CHL * BD + (size_t)q * 4 + BD;

    float4 cur[4], nxt[4];
#pragma unroll
    for (int j = 0; j < 4; ++j) cur[j] = *(const float4*)&pp[(size_t)j * BD];
    for (int g = 0; g < CHL / 4; ++g) {
        if (g + 1 < CHL / 4) {
#pragma unroll
            for (int j = 0; j < 4; ++j)
                nxt[j] = *(const float4*)&pp[(size_t)((g + 1) * 4 + j) * BD];
        }
#pragma unroll
        for (int j = 0; j < 4; ++j) {
            const size_t so = (size_t)(g * 4 + j) * BD;
            stepH(cur[j].x, h.x);
            stepH(cur[j].y, h.y);
            stepH(cur[j].z, h.z);
            stepH(cur[j].w, h.w);
            float4 o;
            o.x = outOf(h.x); o.y = outOf(h.y); o.z = outOf(h.z); o.w = outOf(h.w);
            *(float4*)&pp[so] = o;
            *(float4*)&hp[so] = h;
        }
#pragma unroll
        for (int j = 0; j < 4; ++j) cur[j] = nxt[j];
    }
}

// ---------- last-resort sequential scan ----------
__global__ __launch_bounds__(64) void scan_fused(float* __restrict__ po,
                                                 float* __restrict__ h_out) {
    const int idx = (int)blockIdx.x * 64 + (int)threadIdx.x;
    float h = 0.f;
    h_out[idx] = 0.f;
    size_t off = (size_t)idx;
#pragma unroll 4
    for (int t = 0; t < T_DIM; ++t) {
        float p = po[off];
        stepH(p, h);
        po[off] = outOf(h);
        h_out[off + BD] = h;
        off += BD;
    }
}

extern "C" void kernel_launch(void* const* d_in, const int* in_sizes, int n_in,
                              void* d_out, int out_size, void* d_ws, size_t ws_size,
                              hipStream_t stream) {
    const float* x = (const float*)d_in[0];
    const float* W = (const float*)d_in[1];
    const float* b = (const float*)d_in[2];
    float* out = (float*)d_out;                                // outputs (128 MB)
    float* h   = out + (size_t)T_DIM * B_DIM * D_DIM;          // h region (134.2 MB)

    // Xf/Wh scratch in the h region (dead before pass2 writes h):
    ushort* Xf = (ushort*)h;                                   // 64 MB
    ushort* Wh = Xf + (size_t)M_DIM * K_DIM;                   // 2 MB

    convert_tiles<<<2048, 256, 0, stream>>>(x, Xf);            // 128 slabs x 16 kt
    convert_tiles<<<64, 256, 0, stream>>>(W, Wh);              // 4 slabs x 16 kt

    const size_t P16_BYTES = (size_t)M_DIM * N_DIM * 2;        // 64 MB
    const size_t AB_BYTES  = (size_t)NCH * BD * 4;             // 2 MB each

    if (ws_size >= P16_BYTES + 2 * AB_BYTES) {
        // f16 proj in workspace: half the proj write + both scan reads.
        ushort* P16 = (ushort*)d_ws;
        float*  Ac  = (float*)((char*)d_ws + P16_BYTES);
        float*  Bc  = Ac + (size_t)NCH * BD;
        gemm_proj<1><<<512, 512, 0, stream>>>(Xf, Wh, b, nullptr, P16);
        scan_pass1h<<<(NCH - 1) * 8, 256, 0, stream>>>(P16, Ac, Bc);
        scan_pass2h<<<NCH * 8, 256, 0, stream>>>(P16, Ac, Bc, out, h);
    } else if (ws_size >= (size_t)4 * 1024 * 1024) {
        float4* Ac = (float4*)d_ws;
        float4* Bc = Ac + (size_t)NCH * NQ;
        gemm_proj<0><<<512, 512, 0, stream>>>(Xf, Wh, b, out, nullptr);
        scan_pass1<<<(NCH - 1) * 16, 256, 0, stream>>>(out, Ac, Bc);
        scan_pass2<<<NCH * 16, 256, 0, stream>>>(out, Ac, Bc, h);
    } else {
        gemm_proj<0><<<512, 512, 0, stream>>>(Xf, Wh, b, out, nullptr);
        scan_fused<<<BD / 64, 64, 0, stream>>>(out, h);
    }
}